// Round 9
// baseline (237.824 us; speedup 1.0000x reference)
//
#include <hip/hip_runtime.h>
#include <hip/hip_fp16.h>

// GIN: 2x GINConv(eps=0, MLP 2-layer H=64) + global mean pool + linear.
// N=50000, E=800000, G=2500.
//
// R8: CSR build collapsed to 2 kernels, memset folded away. bin_direct bins
// edges into fixed-capacity bucket regions (CAP=8192 >> mean 4096, 64-sigma
// margin, OOB-guarded) -- no pre-scan needed; the bucket-offset scan runs in
// the last block (fence + done counter + device-scope atomic loads).
// prep = pack_x + zero(sums|counts|bkt_cur|done). 8 dispatches total.

typedef unsigned int uint;

#define BSH  8           // bucket = 256 nodes
#define NBKMAX 256       // >= ceil(50000/256)=196
#define EPB  4096        // edges per block in bin pass
#define CAP  8192        // per-bucket pairs capacity (mean 4096, sd 64)

__device__ __forceinline__ float rlane(float v, int k) {
    return __uint_as_float(__builtin_amdgcn_readlane(__float_as_uint(v), k));
}
__device__ __forceinline__ void addu(float* a, uint d) {
    __half2 h = *(__half2*)&d;
    a[0] += __low2float(h);
    a[1] += __high2float(h);
}

// ---------------- prep: pack x,pos -> f16 rows; zero accumulators ----------

__global__ __launch_bounds__(256) void prep(
    const float* __restrict__ x, const float* __restrict__ pos,
    uint2* __restrict__ xp2, float* __restrict__ zbase, int zero_elems, int N)
{
    for (int idx = blockIdx.x * 256 + threadIdx.x; idx < zero_elems;
         idx += gridDim.x * 256)
        zbase[idx] = 0.f;
    int i = blockIdx.x * 256 + threadIdx.x;
    if (i >= N) return;
    float v[16];
#pragma unroll
    for (int k = 0; k < 11; k++) v[k] = x[(size_t)i * 11 + k];
    v[11] = pos[(size_t)i * 3 + 0];
    v[12] = pos[(size_t)i * 3 + 1];
    v[13] = pos[(size_t)i * 3 + 2];
    v[14] = 0.f; v[15] = 0.f;
#pragma unroll
    for (int c = 0; c < 4; c++) {
        __half2 l = __floats2half2_rn(v[4 * c],     v[4 * c + 1]);
        __half2 h = __floats2half2_rn(v[4 * c + 2], v[4 * c + 3]);
        uint2 u;
        u.x = *(uint*)&l;
        u.y = *(uint*)&h;
        xp2[(size_t)i * 4 + c] = u;
    }
}

// ---------------- bin_direct: one-pass binning + last-block scan ----------

__global__ __launch_bounds__(256) void bin_direct(
    const int* __restrict__ src, const int* __restrict__ dst,
    int* __restrict__ bkt_cur, int* __restrict__ done,
    uint* __restrict__ pairs, int* __restrict__ bkt_off, int nbk, int E)
{
    __shared__ int lcnt[NBKMAX];
    __shared__ int lbase[NBKMAX];
    for (int i = threadIdx.x; i < nbk; i += 256) lcnt[i] = 0;
    __syncthreads();
    int e0 = blockIdx.x * EPB + threadIdx.x;
    uint pv[EPB / 256];
    int  rk[EPB / 256], bk[EPB / 256];
#pragma unroll
    for (int j = 0; j < EPB / 256; j++) {
        int e = e0 + j * 256;
        bk[j] = -1;
        if (e < E) {
            int s = src[e];
            int d = dst[e];
            bk[j] = d >> BSH;
            pv[j] = ((uint)(d & ((1 << BSH) - 1)) << 16) | (uint)s;  // N<65536
            rk[j] = atomicAdd(&lcnt[bk[j]], 1);
        }
    }
    __syncthreads();
    for (int i = threadIdx.x; i < nbk; i += 256) {
        int c = lcnt[i];
        lbase[i] = c ? atomicAdd(&bkt_cur[i], c) : 0;
    }
    __syncthreads();
#pragma unroll
    for (int j = 0; j < EPB / 256; j++) {
        if (bk[j] >= 0) {
            int p = lbase[bk[j]] + rk[j];
            if (p < CAP)                                   // safety guard
                pairs[(size_t)bk[j] * CAP + p] = pv[j];
        }
    }
    // last block performs the bucket-offset scan
    __threadfence();
    __shared__ int amlast;
    if (threadIdx.x == 0)
        amlast = (atomicAdd(done, 1) == (int)gridDim.x - 1);
    __syncthreads();
    if (!amlast) return;
    __shared__ int wsum[4];
    int i = threadIdx.x;
    int v = 0;
    if (i < nbk)
        v = __hip_atomic_load(&bkt_cur[i], __ATOMIC_RELAXED,
                              __HIP_MEMORY_SCOPE_AGENT);
    int lane = threadIdx.x & 63, w = threadIdx.x >> 6;
    int s = v;
#pragma unroll
    for (int off2 = 1; off2 < 64; off2 <<= 1) {
        int t = __shfl_up(s, off2, 64);
        if (lane >= off2) s += t;
    }
    if (lane == 63) wsum[w] = s;
    __syncthreads();
    int add = 0;
    for (int j = 0; j < w; j++) add += wsum[j];
    int incl = s + add;
    if (i < nbk) bkt_off[i] = incl - v;
    if (i == nbk - 1) bkt_off[nbk] = incl;   // == E
}

// ---------------- bucket_build: per-bucket deg/offs/ssrc (LDS-local) --------

__global__ __launch_bounds__(256) void bucket_build(
    const uint* __restrict__ pairs, const int* __restrict__ bkt_off,
    int* __restrict__ offs, int* __restrict__ deg,
    int* __restrict__ ssrc, int N)
{
    __shared__ int cnt[1 << BSH];
    __shared__ int cur[1 << BSH];
    __shared__ int wsum[4];
    int b = blockIdx.x;
    int nbase = b << BSH;
    int nn = min(1 << BSH, N - nbase);
    cnt[threadIdx.x] = 0;
    __syncthreads();
    int start = bkt_off[b];
    int npair = bkt_off[b + 1] - start;
    const uint* pw = pairs + (size_t)b * CAP;
    for (int e = threadIdx.x; e < npair; e += 256)
        atomicAdd(&cnt[pw[e] >> 16], 1);
    __syncthreads();
    int v = cnt[threadIdx.x];
    int lane = threadIdx.x & 63, w = threadIdx.x >> 6;
    int s = v;
#pragma unroll
    for (int off2 = 1; off2 < 64; off2 <<= 1) {
        int t = __shfl_up(s, off2, 64);
        if (lane >= off2) s += t;
    }
    if (lane == 63) wsum[w] = s;
    __syncthreads();
    int add = 0;
    for (int j = 0; j < w; j++) add += wsum[j];
    int gofs = start + (s + add - v);
    if (threadIdx.x < nn) {
        offs[nbase + threadIdx.x] = gofs;
        deg[nbase + threadIdx.x]  = v;
    }
    cur[threadIdx.x] = gofs;
    __syncthreads();
    for (int e = threadIdx.x; e < npair; e += 256) {
        uint pr = pw[e];
        int p = atomicAdd(&cur[pr >> 16], 1);
        ssrc[p] = (int)(pr & 0xffffu);
    }
}

// ---------------- gather1: z0 = self + sum_nbr xp, 16 rows/load ----------------

__global__ __launch_bounds__(256) void gather1(
    const uint2* __restrict__ xp2,
    const int* __restrict__ offs, const int* __restrict__ deg,
    const int* __restrict__ ssrc,
    float4* __restrict__ z04, int N)
{
    int lane = threadIdx.x & 63;
    int i = blockIdx.x * 4 + (threadIdx.x >> 6);
    if (i >= N) return;
    int j = lane >> 2;           // row slot 0..15
    int c = lane & 3;            // dword-pair: features 4c..4c+3
    int st = offs[i], len = deg[i];
    float a[4] = {0.f, 0.f, 0.f, 0.f};
    int k = 0;
    while (k < len) {
        int chunk = min(len - k, 64);
        int sv = ssrc[st + k + min(lane, chunk - 1)];
        int t = 0;
        for (; t + 32 <= chunk; t += 32) {
            int sA = __shfl(sv, t + j, 64);
            int sB = __shfl(sv, t + 16 + j, 64);
            uint2 A = xp2[(size_t)sA * 4 + c];
            uint2 B = xp2[(size_t)sB * 4 + c];
            addu(a + 0, A.x); addu(a + 2, A.y);
            addu(a + 0, B.x); addu(a + 2, B.y);
        }
        for (; t + 16 <= chunk; t += 16) {
            int sA = __shfl(sv, t + j, 64);
            uint2 A = xp2[(size_t)sA * 4 + c];
            addu(a + 0, A.x); addu(a + 2, A.y);
        }
        if (t < chunk) {
            int r = chunk - t;
            int sA = __shfl(sv, t + min(j, r - 1), 64);
            uint2 A = xp2[(size_t)sA * 4 + c];
            if (j < r) { addu(a + 0, A.x); addu(a + 2, A.y); }
        }
        k += chunk;
    }
#pragma unroll
    for (int m = 4; m < 64; m <<= 1)
#pragma unroll
        for (int d = 0; d < 4; d++) a[d] += __shfl_xor(a[d], m, 64);
    uint2 S = xp2[(size_t)i * 4 + c];            // self
    addu(a + 0, S.x); addu(a + 2, S.y);
    if (lane < 4) {
        float4 f; f.x = a[0]; f.y = a[1]; f.z = a[2]; f.w = a[3];
        z04[(size_t)i * 4 + lane] = f;
    }
}

// ---------------- mlp1: h1 = relu(MLP(z0)) -> packed f16 [N x 32 dwords] ----

__global__ __launch_bounds__(256) void mlp1(
    const float* __restrict__ z0,
    const float* __restrict__ W1a, const float* __restrict__ b1a,
    const float* __restrict__ W1b, const float* __restrict__ b1b,
    uint* __restrict__ h1p, int N)
{
    __shared__ float Wa[14 * 64];
    __shared__ float Wb[64 * 64];
    for (int i = threadIdx.x; i < 14 * 64; i += 256) Wa[i] = W1a[i];
    for (int i = threadIdx.x; i < 64 * 64; i += 256) Wb[i] = W1b[i];
    __syncthreads();

    int lane = threadIdx.x & 63;
    int wv = blockIdx.x * 4 + (threadIdx.x >> 6);
    int i0 = wv * 4;
    if (i0 >= N) return;

    float zl = z0[(size_t)i0 * 16 + lane];
    float ba = b1a[lane], bb = b1b[lane];

    float t[4], o[4];
#pragma unroll
    for (int n = 0; n < 4; n++) t[n] = ba;
#pragma unroll
    for (int k = 0; k < 14; k++) {
        float wa = Wa[k * 64 + lane];
#pragma unroll
        for (int n = 0; n < 4; n++) t[n] += rlane(zl, n * 16 + k) * wa;
    }
#pragma unroll
    for (int n = 0; n < 4; n++) { t[n] = fmaxf(t[n], 0.f); o[n] = bb; }
#pragma unroll
    for (int k = 0; k < 64; k++) {
        float wb = Wb[k * 64 + lane];
#pragma unroll
        for (int n = 0; n < 4; n++) o[n] += rlane(t[n], k) * wb;
    }
#pragma unroll
    for (int n = 0; n < 4; n++) o[n] = fmaxf(o[n], 0.f);  // outer relu L1

    int p = lane & 31, half = lane >> 5;
#pragma unroll
    for (int pr = 0; pr < 2; pr++) {
        float lo0 = __shfl(o[2 * pr],     2 * p,     64);
        float hi0 = __shfl(o[2 * pr],     2 * p + 1, 64);
        float lo1 = __shfl(o[2 * pr + 1], 2 * p,     64);
        float hi1 = __shfl(o[2 * pr + 1], 2 * p + 1, 64);
        float lo = half ? lo1 : lo0;
        float hi = half ? hi1 : hi0;
        __half2 h = __halves2half2(__float2half(lo), __float2half(hi));
        h1p[(size_t)(i0 + 2 * pr + half) * 32 + p] = *(uint*)&h;
    }
}

// ---------------- gather2: z1 = self + sum_nbr h1, 8 rows/load ----------------

__global__ __launch_bounds__(256) void gather2(
    const uint4* __restrict__ h4,
    const int* __restrict__ offs, const int* __restrict__ deg,
    const int* __restrict__ ssrc,
    uint4* __restrict__ z4, int N)
{
    int lane = threadIdx.x & 63;
    int i = blockIdx.x * 4 + (threadIdx.x >> 6);
    if (i >= N) return;
    int j = lane >> 3;           // row slot 0..7
    int q = lane & 7;            // uint4 index: features 8q..8q+7
    int st = offs[i], len = deg[i];
    float a[8] = {0.f, 0.f, 0.f, 0.f, 0.f, 0.f, 0.f, 0.f};
    int k = 0;
    while (k < len) {
        int chunk = min(len - k, 64);
        int sv = ssrc[st + k + min(lane, chunk - 1)];
        int t = 0;
        for (; t + 32 <= chunk; t += 32) {
            int sA = __shfl(sv, t + j, 64);
            int sB = __shfl(sv, t + 8 + j, 64);
            int sC = __shfl(sv, t + 16 + j, 64);
            int sD = __shfl(sv, t + 24 + j, 64);
            uint4 A = h4[(size_t)sA * 8 + q];
            uint4 B = h4[(size_t)sB * 8 + q];
            uint4 C = h4[(size_t)sC * 8 + q];
            uint4 D = h4[(size_t)sD * 8 + q];
            addu(a + 0, A.x); addu(a + 2, A.y); addu(a + 4, A.z); addu(a + 6, A.w);
            addu(a + 0, B.x); addu(a + 2, B.y); addu(a + 4, B.z); addu(a + 6, B.w);
            addu(a + 0, C.x); addu(a + 2, C.y); addu(a + 4, C.z); addu(a + 6, C.w);
            addu(a + 0, D.x); addu(a + 2, D.y); addu(a + 4, D.z); addu(a + 6, D.w);
        }
        for (; t + 16 <= chunk; t += 16) {
            int sA = __shfl(sv, t + j, 64);
            int sB = __shfl(sv, t + 8 + j, 64);
            uint4 A = h4[(size_t)sA * 8 + q];
            uint4 B = h4[(size_t)sB * 8 + q];
            addu(a + 0, A.x); addu(a + 2, A.y); addu(a + 4, A.z); addu(a + 6, A.w);
            addu(a + 0, B.x); addu(a + 2, B.y); addu(a + 4, B.z); addu(a + 6, B.w);
        }
        for (; t + 8 <= chunk; t += 8) {
            int sA = __shfl(sv, t + j, 64);
            uint4 A = h4[(size_t)sA * 8 + q];
            addu(a + 0, A.x); addu(a + 2, A.y); addu(a + 4, A.z); addu(a + 6, A.w);
        }
        if (t < chunk) {
            int r = chunk - t;
            int sA = __shfl(sv, t + min(j, r - 1), 64);
            uint4 A = h4[(size_t)sA * 8 + q];
            if (j < r) {
                addu(a + 0, A.x); addu(a + 2, A.y);
                addu(a + 4, A.z); addu(a + 6, A.w);
            }
        }
        k += chunk;
    }
#pragma unroll
    for (int m = 8; m < 64; m <<= 1)
#pragma unroll
        for (int d = 0; d < 8; d++) a[d] += __shfl_xor(a[d], m, 64);
    uint4 S = h4[(size_t)i * 8 + q];             // self
    addu(a + 0, S.x); addu(a + 2, S.y); addu(a + 4, S.z); addu(a + 6, S.w);
    if (lane < 8) {
        __half2 p0 = __floats2half2_rn(a[0], a[1]);
        __half2 p1 = __floats2half2_rn(a[2], a[3]);
        __half2 p2 = __floats2half2_rn(a[4], a[5]);
        __half2 p3 = __floats2half2_rn(a[6], a[7]);
        uint4 o4;
        o4.x = *(uint*)&p0; o4.y = *(uint*)&p1;
        o4.z = *(uint*)&p2; o4.w = *(uint*)&p3;
        z4[(size_t)i * 8 + lane] = o4;
    }
}

// ---------------- mlp2 + pooling ----------------

__global__ __launch_bounds__(256) void mlp2pool(
    const uint* __restrict__ z1p,
    const float* __restrict__ W2a, const float* __restrict__ b2a,
    const float* __restrict__ W2b, const float* __restrict__ b2b,
    const int* __restrict__ batch,
    float* __restrict__ sums, float* __restrict__ counts, int N)
{
    __shared__ float Wa[64 * 64];
    __shared__ float Wb[64 * 64];
    for (int i = threadIdx.x; i < 64 * 64; i += 256) {
        Wa[i] = W2a[i];
        Wb[i] = W2b[i];
    }
    __syncthreads();

    int lane = threadIdx.x & 63;
    int wv = blockIdx.x * 4 + (threadIdx.x >> 6);
    int i0 = wv * 4;
    if (i0 >= N) return;
    float ba = b2a[lane], bb = b2b[lane];

    float zl[4];
#pragma unroll
    for (int n = 0; n < 4; n++) {
        uint d = z1p[(size_t)(i0 + n) * 32 + (lane >> 1)];
        __half2 h = *(__half2*)&d;
        zl[n] = (lane & 1) ? __high2float(h) : __low2float(h);
    }

    float t[4], o[4];
#pragma unroll
    for (int n = 0; n < 4; n++) t[n] = ba;
#pragma unroll
    for (int k = 0; k < 64; k++) {
        float wa = Wa[k * 64 + lane];
#pragma unroll
        for (int n = 0; n < 4; n++) t[n] += rlane(zl[n], k) * wa;
    }
#pragma unroll
    for (int n = 0; n < 4; n++) { t[n] = fmaxf(t[n], 0.f); o[n] = bb; }
#pragma unroll
    for (int k = 0; k < 64; k++) {
        float wb = Wb[k * 64 + lane];
#pragma unroll
        for (int n = 0; n < 4; n++) o[n] += rlane(t[n], k) * wb;
    }

    int gcur = batch[i0]; float ps = 0.f; int cnt = 0;
#pragma unroll
    for (int n = 0; n < 4; n++) {
        float h2 = fmaxf(o[n], 0.f);
        int gi = batch[i0 + n];
        if (gi != gcur) {
            atomicAdd(&sums[gcur * 64 + lane], ps);
            if (lane == 0) atomicAdd(&counts[gcur], (float)cnt);
            gcur = gi; ps = 0.f; cnt = 0;
        }
        ps += h2; cnt++;
    }
    atomicAdd(&sums[gcur * 64 + lane], ps);
    if (lane == 0) atomicAdd(&counts[gcur], (float)cnt);
}

__global__ __launch_bounds__(256) void gin_final(
    const float* __restrict__ sums, const float* __restrict__ counts,
    const float* __restrict__ Wlin, const float* __restrict__ blin,
    float* __restrict__ out, int G)
{
    int lane = threadIdx.x & 63;
    int g    = blockIdx.x * 4 + (threadIdx.x >> 6);
    if (g < G) {
        float v = sums[g * 64 + lane] * Wlin[lane];
#pragma unroll
        for (int off = 32; off > 0; off >>= 1) v += __shfl_down(v, off, 64);
        if (lane == 0) out[g] = v / fmaxf(counts[g], 1.0f) + blin[0];
    }
}

extern "C" void kernel_launch(void* const* d_in, const int* in_sizes, int n_in,
                              void* d_out, int out_size, void* d_ws, size_t ws_size,
                              hipStream_t stream) {
    const float* x    = (const float*)d_in[0];
    const float* pos  = (const float*)d_in[1];
    const int*   ei   = (const int*)d_in[2];
    const int*   batch= (const int*)d_in[3];
    const float* W1a  = (const float*)d_in[4];
    const float* b1a  = (const float*)d_in[5];
    const float* W1b  = (const float*)d_in[6];
    const float* b1b  = (const float*)d_in[7];
    const float* W2a  = (const float*)d_in[8];
    const float* b2a  = (const float*)d_in[9];
    const float* W2b  = (const float*)d_in[10];
    const float* b2b  = (const float*)d_in[11];
    const float* Wlin = (const float*)d_in[12];
    const float* blin = (const float*)d_in[13];
    float* out = (float*)d_out;

    const int N = in_sizes[0] / 11;     // 50000 (must be < 65536 for u32 pairs)
    const int E = in_sizes[2] / 2;      // 800000
    const int G = out_size;             // 2500

    const int* src = ei;
    const int* dst = ei + E;
    const int nbk = (N + (1 << BSH) - 1) >> BSH;   // 196
    const int neb = (E + EPB - 1) / EPB;           // 196

    // Workspace:
    // [sums|counts|bkt_cur|done] (zeroed by prep) |bkt_off|offs|deg|ssrc|h1p|xp|
    // zunion { pairs (nbk*CAP u32) / z0 (N*16 f32) / z1p (N*32 u32) }
    char* ws = (char*)d_ws;
    size_t o = 0;
    float* sums    = (float*)(ws + o); o += (size_t)G * 64 * 4;
    float* counts  = (float*)(ws + o); o += (((size_t)G + 63) & ~(size_t)63) * 4;
    int*   bkt_cur = (int*)(ws + o);   o += NBKMAX * 4;
    int*   done    = (int*)(ws + o);   o += 64 * 4;
    size_t zero_bytes = o;             // everything above zeroed by prep
    int*   bkt_off = (int*)(ws + o);   o += (NBKMAX + 1) * 4;
    int*   offs    = (int*)(ws + o);   o += (size_t)N * 4;
    int*   deg     = (int*)(ws + o);   o += (size_t)N * 4;
    int*   ssrc    = (int*)(ws + o);   o += (size_t)E * 4;
    o = (o + 255) & ~(size_t)255;
    uint*  h1p     = (uint*)(ws + o);  o += (size_t)N * 32 * 4;
    o = (o + 255) & ~(size_t)255;
    uint2* xp2     = (uint2*)(ws + o); o += (size_t)N * 32;
    o = (o + 255) & ~(size_t)255;
    uint*  pairs   = (uint*)(ws + o);  // nbk*CAP u32 (6.4 MB) } time-disjoint
    float* z0      = (float*)(ws + o); // N*16 f32 (3.2 MB)    } union
    uint*  z1p     = (uint*)(ws + o);  // N*32 u32 (6.4 MB)    }

    const int zero_elems = (int)(zero_bytes / 4);

    prep<<<(N + 255) / 256, 256, 0, stream>>>(
        x, pos, xp2, (float*)ws, zero_elems, N);
    bin_direct<<<neb, 256, 0, stream>>>(
        src, dst, bkt_cur, done, pairs, bkt_off, nbk, E);
    bucket_build<<<nbk, 256, 0, stream>>>(pairs, bkt_off, offs, deg, ssrc, N);

    gather1<<<(N + 3) / 4, 256, 0, stream>>>(
        xp2, offs, deg, ssrc, (float4*)z0, N);
    mlp1<<<(N + 15) / 16, 256, 0, stream>>>(z0, W1a, b1a, W1b, b1b, h1p, N);
    gather2<<<(N + 3) / 4, 256, 0, stream>>>(
        (const uint4*)h1p, offs, deg, ssrc, (uint4*)z1p, N);
    mlp2pool<<<(N + 15) / 16, 256, 0, stream>>>(
        z1p, W2a, b2a, W2b, b2b, batch, sums, counts, N);

    gin_final<<<(G + 3) / 4, 256, 0, stream>>>(
        sums, counts, Wlin, blin, out, G);
}

// Round 10
// 230.878 us; speedup vs baseline: 1.0301x; 1.0301x over previous
//
#include <hip/hip_runtime.h>
#include <hip/hip_fp16.h>

// GIN: 2x GINConv(eps=0, MLP 2-layer H=64) + global mean pool + linear.
// N=50000, E=800000, G=2500.
//
// R9: revert CSR build to R7's measured-good 4-kernel bucket scheme (R8's
// bin_direct regressed). NEW: mlp1/mlp2pool are PERSISTENT -- 1024 blocks
// stage weights into LDS once and grid-stride over node groups (R8 profile:
// mlp2pool 54us, VALUBusy 48% -- per-block 32KB weight staging for only 16
// nodes of work was the bottleneck).

typedef unsigned int uint;

#define BSH  8           // bucket = 256 nodes
#define NBKMAX 256       // >= ceil(50000/256)=196
#define EPB  4096        // edges per block in hist/bin passes
#define MLPBLK 1024      // persistent MLP grid

__device__ __forceinline__ float rlane(float v, int k) {
    return __uint_as_float(__builtin_amdgcn_readlane(__float_as_uint(v), k));
}
__device__ __forceinline__ void addu(float* a, uint d) {
    __half2 h = *(__half2*)&d;
    a[0] += __low2float(h);
    a[1] += __high2float(h);
}

// ---------------- pack x,pos -> f16 rows [N x 32B] ----------------

__global__ __launch_bounds__(256) void pack_x(
    const float* __restrict__ x, const float* __restrict__ pos,
    uint2* __restrict__ xp2, int N)
{
    int i = blockIdx.x * 256 + threadIdx.x;
    if (i >= N) return;
    float v[16];
#pragma unroll
    for (int k = 0; k < 11; k++) v[k] = x[(size_t)i * 11 + k];
    v[11] = pos[(size_t)i * 3 + 0];
    v[12] = pos[(size_t)i * 3 + 1];
    v[13] = pos[(size_t)i * 3 + 2];
    v[14] = 0.f; v[15] = 0.f;
#pragma unroll
    for (int c = 0; c < 4; c++) {
        __half2 l = __floats2half2_rn(v[4 * c],     v[4 * c + 1]);
        __half2 h = __floats2half2_rn(v[4 * c + 2], v[4 * c + 3]);
        uint2 u;
        u.x = *(uint*)&l;
        u.y = *(uint*)&h;
        xp2[(size_t)i * 4 + c] = u;
    }
}

// ---------------- bucket histogram (LDS-privatized) ----------------

__global__ __launch_bounds__(256) void bucket_hist(
    const int* __restrict__ dst, int* __restrict__ bkt_cnt, int nbk, int E)
{
    __shared__ int lb[NBKMAX];
    for (int i = threadIdx.x; i < nbk; i += 256) lb[i] = 0;
    __syncthreads();
    int e0 = blockIdx.x * EPB + threadIdx.x;
#pragma unroll
    for (int j = 0; j < EPB / 256; j++) {
        int e = e0 + j * 256;
        if (e < E) atomicAdd(&lb[dst[e] >> BSH], 1);
    }
    __syncthreads();
    for (int i = threadIdx.x; i < nbk; i += 256) {
        int c = lb[i];
        if (c) atomicAdd(&bkt_cnt[i], c);
    }
}

// ---------------- bucket-offset scan (single block) ----------------

__global__ __launch_bounds__(256) void scan_small(
    const int* __restrict__ cnt, int* __restrict__ off,
    int* __restrict__ cur, int nbk)
{
    __shared__ int wsum[4];
    int i = threadIdx.x;
    int v = (i < nbk) ? cnt[i] : 0;
    int lane = threadIdx.x & 63, w = threadIdx.x >> 6;
    int s = v;
#pragma unroll
    for (int off2 = 1; off2 < 64; off2 <<= 1) {
        int t = __shfl_up(s, off2, 64);
        if (lane >= off2) s += t;
    }
    if (lane == 63) wsum[w] = s;
    __syncthreads();
    int add = 0;
    for (int j = 0; j < w; j++) add += wsum[j];
    int incl = s + add;
    if (i < nbk) { off[i] = incl - v; cur[i] = incl - v; }
    if (i == nbk - 1) off[nbk] = incl;   // == E
}

// ---------------- pass 1: bin edges into bucket-contiguous runs ----------------

__global__ __launch_bounds__(256) void bin_pairs(
    const int* __restrict__ src, const int* __restrict__ dst,
    int* __restrict__ bkt_cur, uint* __restrict__ pairs, int nbk, int E)
{
    __shared__ int lcnt[NBKMAX];
    __shared__ int lbase[NBKMAX];
    for (int i = threadIdx.x; i < nbk; i += 256) lcnt[i] = 0;
    __syncthreads();
    int e0 = blockIdx.x * EPB + threadIdx.x;
    uint pv[EPB / 256];
    int  rk[EPB / 256], bk[EPB / 256];
#pragma unroll
    for (int j = 0; j < EPB / 256; j++) {
        int e = e0 + j * 256;
        bk[j] = -1;
        if (e < E) {
            int s = src[e];
            int d = dst[e];
            bk[j] = d >> BSH;
            pv[j] = ((uint)(d & ((1 << BSH) - 1)) << 16) | (uint)s;  // N<65536
            rk[j] = atomicAdd(&lcnt[bk[j]], 1);
        }
    }
    __syncthreads();
    for (int i = threadIdx.x; i < nbk; i += 256) {
        int c = lcnt[i];
        lbase[i] = c ? atomicAdd(&bkt_cur[i], c) : 0;
    }
    __syncthreads();
#pragma unroll
    for (int j = 0; j < EPB / 256; j++) {
        if (bk[j] >= 0)
            pairs[(size_t)lbase[bk[j]] + rk[j]] = pv[j];
    }
}

// ---------------- pass 2: per-bucket deg/offs/ssrc (all LDS-local) ----------

__global__ __launch_bounds__(256) void bucket_build(
    const uint* __restrict__ pairs, const int* __restrict__ bkt_off,
    int* __restrict__ offs, int* __restrict__ deg,
    int* __restrict__ ssrc, int N)
{
    __shared__ int cnt[1 << BSH];
    __shared__ int cur[1 << BSH];
    __shared__ int wsum[4];
    int b = blockIdx.x;
    int nbase = b << BSH;
    int nn = min(1 << BSH, N - nbase);
    cnt[threadIdx.x] = 0;
    __syncthreads();
    int start = bkt_off[b], end = bkt_off[b + 1];
    for (int e = start + threadIdx.x; e < end; e += 256)
        atomicAdd(&cnt[pairs[e] >> 16], 1);
    __syncthreads();
    int v = cnt[threadIdx.x];
    int lane = threadIdx.x & 63, w = threadIdx.x >> 6;
    int s = v;
#pragma unroll
    for (int off2 = 1; off2 < 64; off2 <<= 1) {
        int t = __shfl_up(s, off2, 64);
        if (lane >= off2) s += t;
    }
    if (lane == 63) wsum[w] = s;
    __syncthreads();
    int add = 0;
    for (int j = 0; j < w; j++) add += wsum[j];
    int gofs = start + (s + add - v);
    if (threadIdx.x < nn) {
        offs[nbase + threadIdx.x] = gofs;
        deg[nbase + threadIdx.x]  = v;
    }
    cur[threadIdx.x] = gofs;
    __syncthreads();
    for (int e = start + threadIdx.x; e < end; e += 256) {
        uint pr = pairs[e];
        int p = atomicAdd(&cur[pr >> 16], 1);
        ssrc[p] = (int)(pr & 0xffffu);
    }
}

// ---------------- gather1: z0 = self + sum_nbr xp, 16 rows/load ----------------

__global__ __launch_bounds__(256) void gather1(
    const uint2* __restrict__ xp2,
    const int* __restrict__ offs, const int* __restrict__ deg,
    const int* __restrict__ ssrc,
    float4* __restrict__ z04, int N)
{
    int lane = threadIdx.x & 63;
    int i = blockIdx.x * 4 + (threadIdx.x >> 6);
    if (i >= N) return;
    int j = lane >> 2;           // row slot 0..15
    int c = lane & 3;            // dword-pair: features 4c..4c+3
    int st = offs[i], len = deg[i];
    float a[4] = {0.f, 0.f, 0.f, 0.f};
    int k = 0;
    while (k < len) {
        int chunk = min(len - k, 64);
        int sv = ssrc[st + k + min(lane, chunk - 1)];
        int t = 0;
        for (; t + 32 <= chunk; t += 32) {
            int sA = __shfl(sv, t + j, 64);
            int sB = __shfl(sv, t + 16 + j, 64);
            uint2 A = xp2[(size_t)sA * 4 + c];
            uint2 B = xp2[(size_t)sB * 4 + c];
            addu(a + 0, A.x); addu(a + 2, A.y);
            addu(a + 0, B.x); addu(a + 2, B.y);
        }
        for (; t + 16 <= chunk; t += 16) {
            int sA = __shfl(sv, t + j, 64);
            uint2 A = xp2[(size_t)sA * 4 + c];
            addu(a + 0, A.x); addu(a + 2, A.y);
        }
        if (t < chunk) {
            int r = chunk - t;
            int sA = __shfl(sv, t + min(j, r - 1), 64);
            uint2 A = xp2[(size_t)sA * 4 + c];
            if (j < r) { addu(a + 0, A.x); addu(a + 2, A.y); }
        }
        k += chunk;
    }
#pragma unroll
    for (int m = 4; m < 64; m <<= 1)
#pragma unroll
        for (int d = 0; d < 4; d++) a[d] += __shfl_xor(a[d], m, 64);
    uint2 S = xp2[(size_t)i * 4 + c];            // self
    addu(a + 0, S.x); addu(a + 2, S.y);
    if (lane < 4) {
        float4 f; f.x = a[0]; f.y = a[1]; f.z = a[2]; f.w = a[3];
        z04[(size_t)i * 4 + lane] = f;
    }
}

// ---------------- mlp1 (persistent): relu(MLP(z0)) -> packed f16 ----------

__global__ __launch_bounds__(256) void mlp1(
    const float* __restrict__ z0,
    const float* __restrict__ W1a, const float* __restrict__ b1a,
    const float* __restrict__ W1b, const float* __restrict__ b1b,
    uint* __restrict__ h1p, int N)
{
    __shared__ float Wa[14 * 64];
    __shared__ float Wb[64 * 64];
    for (int i = threadIdx.x; i < 14 * 64; i += 256) Wa[i] = W1a[i];
    for (int i = threadIdx.x; i < 64 * 64; i += 256) Wb[i] = W1b[i];
    __syncthreads();

    int lane = threadIdx.x & 63;
    int wv0 = blockIdx.x * 4 + (threadIdx.x >> 6);
    float ba = b1a[lane], bb = b1b[lane];
    int p = lane & 31, half = lane >> 5;
    const int NG = N >> 2;                  // node groups of 4 (N%4==0)

    for (int g = wv0; g < NG; g += MLPBLK * 4) {
        int i0 = g * 4;
        float zl = z0[(size_t)i0 * 16 + lane];

        float t[4], o[4];
#pragma unroll
        for (int n = 0; n < 4; n++) t[n] = ba;
#pragma unroll
        for (int k = 0; k < 14; k++) {
            float wa = Wa[k * 64 + lane];
#pragma unroll
            for (int n = 0; n < 4; n++) t[n] += rlane(zl, n * 16 + k) * wa;
        }
#pragma unroll
        for (int n = 0; n < 4; n++) { t[n] = fmaxf(t[n], 0.f); o[n] = bb; }
#pragma unroll
        for (int k = 0; k < 64; k++) {
            float wb = Wb[k * 64 + lane];
#pragma unroll
            for (int n = 0; n < 4; n++) o[n] += rlane(t[n], k) * wb;
        }
#pragma unroll
        for (int n = 0; n < 4; n++) o[n] = fmaxf(o[n], 0.f);  // outer relu L1

#pragma unroll
        for (int pr = 0; pr < 2; pr++) {
            float lo0 = __shfl(o[2 * pr],     2 * p,     64);
            float hi0 = __shfl(o[2 * pr],     2 * p + 1, 64);
            float lo1 = __shfl(o[2 * pr + 1], 2 * p,     64);
            float hi1 = __shfl(o[2 * pr + 1], 2 * p + 1, 64);
            float lo = half ? lo1 : lo0;
            float hi = half ? hi1 : hi0;
            __half2 h = __halves2half2(__float2half(lo), __float2half(hi));
            h1p[(size_t)(i0 + 2 * pr + half) * 32 + p] = *(uint*)&h;
        }
    }
}

// ---------------- gather2: z1 = self + sum_nbr h1, 8 rows/load ----------------

__global__ __launch_bounds__(256) void gather2(
    const uint4* __restrict__ h4,
    const int* __restrict__ offs, const int* __restrict__ deg,
    const int* __restrict__ ssrc,
    uint4* __restrict__ z4, int N)
{
    int lane = threadIdx.x & 63;
    int i = blockIdx.x * 4 + (threadIdx.x >> 6);
    if (i >= N) return;
    int j = lane >> 3;           // row slot 0..7
    int q = lane & 7;            // uint4 index: features 8q..8q+7
    int st = offs[i], len = deg[i];
    float a[8] = {0.f, 0.f, 0.f, 0.f, 0.f, 0.f, 0.f, 0.f};
    int k = 0;
    while (k < len) {
        int chunk = min(len - k, 64);
        int sv = ssrc[st + k + min(lane, chunk - 1)];
        int t = 0;
        for (; t + 32 <= chunk; t += 32) {
            int sA = __shfl(sv, t + j, 64);
            int sB = __shfl(sv, t + 8 + j, 64);
            int sC = __shfl(sv, t + 16 + j, 64);
            int sD = __shfl(sv, t + 24 + j, 64);
            uint4 A = h4[(size_t)sA * 8 + q];
            uint4 B = h4[(size_t)sB * 8 + q];
            uint4 C = h4[(size_t)sC * 8 + q];
            uint4 D = h4[(size_t)sD * 8 + q];
            addu(a + 0, A.x); addu(a + 2, A.y); addu(a + 4, A.z); addu(a + 6, A.w);
            addu(a + 0, B.x); addu(a + 2, B.y); addu(a + 4, B.z); addu(a + 6, B.w);
            addu(a + 0, C.x); addu(a + 2, C.y); addu(a + 4, C.z); addu(a + 6, C.w);
            addu(a + 0, D.x); addu(a + 2, D.y); addu(a + 4, D.z); addu(a + 6, D.w);
        }
        for (; t + 16 <= chunk; t += 16) {
            int sA = __shfl(sv, t + j, 64);
            int sB = __shfl(sv, t + 8 + j, 64);
            uint4 A = h4[(size_t)sA * 8 + q];
            uint4 B = h4[(size_t)sB * 8 + q];
            addu(a + 0, A.x); addu(a + 2, A.y); addu(a + 4, A.z); addu(a + 6, A.w);
            addu(a + 0, B.x); addu(a + 2, B.y); addu(a + 4, B.z); addu(a + 6, B.w);
        }
        for (; t + 8 <= chunk; t += 8) {
            int sA = __shfl(sv, t + j, 64);
            uint4 A = h4[(size_t)sA * 8 + q];
            addu(a + 0, A.x); addu(a + 2, A.y); addu(a + 4, A.z); addu(a + 6, A.w);
        }
        if (t < chunk) {
            int r = chunk - t;
            int sA = __shfl(sv, t + min(j, r - 1), 64);
            uint4 A = h4[(size_t)sA * 8 + q];
            if (j < r) {
                addu(a + 0, A.x); addu(a + 2, A.y);
                addu(a + 4, A.z); addu(a + 6, A.w);
            }
        }
        k += chunk;
    }
#pragma unroll
    for (int m = 8; m < 64; m <<= 1)
#pragma unroll
        for (int d = 0; d < 8; d++) a[d] += __shfl_xor(a[d], m, 64);
    uint4 S = h4[(size_t)i * 8 + q];             // self
    addu(a + 0, S.x); addu(a + 2, S.y); addu(a + 4, S.z); addu(a + 6, S.w);
    if (lane < 8) {
        __half2 p0 = __floats2half2_rn(a[0], a[1]);
        __half2 p1 = __floats2half2_rn(a[2], a[3]);
        __half2 p2 = __floats2half2_rn(a[4], a[5]);
        __half2 p3 = __floats2half2_rn(a[6], a[7]);
        uint4 o4;
        o4.x = *(uint*)&p0; o4.y = *(uint*)&p1;
        o4.z = *(uint*)&p2; o4.w = *(uint*)&p3;
        z4[(size_t)i * 8 + lane] = o4;
    }
}

// ---------------- mlp2 + pooling (persistent) ----------------

__global__ __launch_bounds__(256) void mlp2pool(
    const uint* __restrict__ z1p,
    const float* __restrict__ W2a, const float* __restrict__ b2a,
    const float* __restrict__ W2b, const float* __restrict__ b2b,
    const int* __restrict__ batch,
    float* __restrict__ sums, float* __restrict__ counts, int N)
{
    __shared__ float Wa[64 * 64];
    __shared__ float Wb[64 * 64];
    for (int i = threadIdx.x; i < 64 * 64; i += 256) {
        Wa[i] = W2a[i];
        Wb[i] = W2b[i];
    }
    __syncthreads();

    int lane = threadIdx.x & 63;
    int wv0 = blockIdx.x * 4 + (threadIdx.x >> 6);
    float ba = b2a[lane], bb = b2b[lane];
    const int NG = N >> 2;                  // node groups of 4 (N%4==0)

    for (int g = wv0; g < NG; g += MLPBLK * 4) {
        int i0 = g * 4;

        float zl[4];
#pragma unroll
        for (int n = 0; n < 4; n++) {
            uint d = z1p[(size_t)(i0 + n) * 32 + (lane >> 1)];
            __half2 h = *(__half2*)&d;
            zl[n] = (lane & 1) ? __high2float(h) : __low2float(h);
        }

        float t[4], o[4];
#pragma unroll
        for (int n = 0; n < 4; n++) t[n] = ba;
#pragma unroll
        for (int k = 0; k < 64; k++) {
            float wa = Wa[k * 64 + lane];
#pragma unroll
            for (int n = 0; n < 4; n++) t[n] += rlane(zl[n], k) * wa;
        }
#pragma unroll
        for (int n = 0; n < 4; n++) { t[n] = fmaxf(t[n], 0.f); o[n] = bb; }
#pragma unroll
        for (int k = 0; k < 64; k++) {
            float wb = Wb[k * 64 + lane];
#pragma unroll
            for (int n = 0; n < 4; n++) o[n] += rlane(t[n], k) * wb;
        }

        int gcur = batch[i0]; float ps = 0.f; int cnt = 0;
#pragma unroll
        for (int n = 0; n < 4; n++) {
            float h2 = fmaxf(o[n], 0.f);
            int gi = batch[i0 + n];
            if (gi != gcur) {
                atomicAdd(&sums[gcur * 64 + lane], ps);
                if (lane == 0) atomicAdd(&counts[gcur], (float)cnt);
                gcur = gi; ps = 0.f; cnt = 0;
            }
            ps += h2; cnt++;
        }
        atomicAdd(&sums[gcur * 64 + lane], ps);
        if (lane == 0) atomicAdd(&counts[gcur], (float)cnt);
    }
}

__global__ __launch_bounds__(256) void gin_final(
    const float* __restrict__ sums, const float* __restrict__ counts,
    const float* __restrict__ Wlin, const float* __restrict__ blin,
    float* __restrict__ out, int G)
{
    int lane = threadIdx.x & 63;
    int g    = blockIdx.x * 4 + (threadIdx.x >> 6);
    if (g < G) {
        float v = sums[g * 64 + lane] * Wlin[lane];
#pragma unroll
        for (int off = 32; off > 0; off >>= 1) v += __shfl_down(v, off, 64);
        if (lane == 0) out[g] = v / fmaxf(counts[g], 1.0f) + blin[0];
    }
}

extern "C" void kernel_launch(void* const* d_in, const int* in_sizes, int n_in,
                              void* d_out, int out_size, void* d_ws, size_t ws_size,
                              hipStream_t stream) {
    const float* x    = (const float*)d_in[0];
    const float* pos  = (const float*)d_in[1];
    const int*   ei   = (const int*)d_in[2];
    const int*   batch= (const int*)d_in[3];
    const float* W1a  = (const float*)d_in[4];
    const float* b1a  = (const float*)d_in[5];
    const float* W1b  = (const float*)d_in[6];
    const float* b1b  = (const float*)d_in[7];
    const float* W2a  = (const float*)d_in[8];
    const float* b2a  = (const float*)d_in[9];
    const float* W2b  = (const float*)d_in[10];
    const float* b2b  = (const float*)d_in[11];
    const float* Wlin = (const float*)d_in[12];
    const float* blin = (const float*)d_in[13];
    float* out = (float*)d_out;

    const int N = in_sizes[0] / 11;     // 50000 (must be < 65536 for u32 pairs)
    const int E = in_sizes[2] / 2;      // 800000
    const int G = out_size;             // 2500

    const int* src = ei;
    const int* dst = ei + E;
    const int nbk = (N + (1 << BSH) - 1) >> BSH;   // 196
    const int neb = (E + EPB - 1) / EPB;           // 196

    // Workspace:
    // [sums|counts|bkt_cnt](memset) |offs|deg|bkt_off|bkt_cur|ssrc|h1p|xp|
    // zunion { pairs (E u32) / z0 (N*16 f32) / z1p (N*32 u32) } time-disjoint
    char* ws = (char*)d_ws;
    size_t o = 0;
    float* sums    = (float*)(ws + o); o += (size_t)G * 64 * 4;
    float* counts  = (float*)(ws + o); o += (((size_t)G + 63) & ~(size_t)63) * 4;
    int*   bkt_cnt = (int*)(ws + o);   o += NBKMAX * 4;
    size_t zero_bytes = o;
    int*   offs    = (int*)(ws + o);   o += (size_t)N * 4;
    int*   deg     = (int*)(ws + o);   o += (size_t)N * 4;
    int*   bkt_off = (int*)(ws + o);   o += (NBKMAX + 1) * 4;
    int*   bkt_cur = (int*)(ws + o);   o += NBKMAX * 4;
    int*   ssrc    = (int*)(ws + o);   o += (size_t)E * 4;
    o = (o + 255) & ~(size_t)255;
    uint*  h1p     = (uint*)(ws + o);  o += (size_t)N * 32 * 4;
    o = (o + 255) & ~(size_t)255;
    uint2* xp2     = (uint2*)(ws + o); o += (size_t)N * 32;
    o = (o + 255) & ~(size_t)255;
    uint*  pairs   = (uint*)(ws + o);  // E u32 (3.2 MB)  } dead before gather1
    float* z0      = (float*)(ws + o); // N*16 f32 (3.2MB)} dead after mlp1
    uint*  z1p     = (uint*)(ws + o);  // N*32 u32 (6.4MB)} written by gather2

    hipMemsetAsync(ws, 0, zero_bytes, stream);

    pack_x<<<(N + 255) / 256, 256, 0, stream>>>(x, pos, xp2, N);
    bucket_hist<<<neb, 256, 0, stream>>>(dst, bkt_cnt, nbk, E);
    scan_small<<<1, 256, 0, stream>>>(bkt_cnt, bkt_off, bkt_cur, nbk);
    bin_pairs<<<neb, 256, 0, stream>>>(src, dst, bkt_cur, pairs, nbk, E);
    bucket_build<<<nbk, 256, 0, stream>>>(pairs, bkt_off, offs, deg, ssrc, N);

    gather1<<<(N + 3) / 4, 256, 0, stream>>>(
        xp2, offs, deg, ssrc, (float4*)z0, N);
    mlp1<<<MLPBLK, 256, 0, stream>>>(z0, W1a, b1a, W1b, b1b, h1p, N);
    gather2<<<(N + 3) / 4, 256, 0, stream>>>(
        (const uint4*)h1p, offs, deg, ssrc, (uint4*)z1p, N);
    mlp2pool<<<MLPBLK, 256, 0, stream>>>(
        z1p, W2a, b2a, W2b, b2b, batch, sums, counts, N);

    gin_final<<<(G + 3) / 4, 256, 0, stream>>>(
        sums, counts, Wlin, blin, out, G);
}

// Round 11
// 191.264 us; speedup vs baseline: 1.2434x; 1.2071x over previous
//
#include <hip/hip_runtime.h>
#include <hip/hip_fp16.h>

// GIN: 2x GINConv(eps=0, MLP 2-layer H=64) + global mean pool + linear.
// N=50000, E=800000, G=2500.
//
// R10: MLPs moved to MFMA (v_mfma_f32_16x16x32_f16). One wave per 16-node
// group; weight B-fragments built once per wave into VGPRs (zero LDS weight
// traffic in steady state); layer->layer relayout via wave-private LDS;
// bias as accumulator init; mlp2 fuses register pooling. gather1 now emits
// f16 z0 rows. CSR build + gathers unchanged from R9 (R7-proven).

typedef unsigned int uint;
typedef _Float16 half8 __attribute__((ext_vector_type(8)));
typedef float f32x4 __attribute__((ext_vector_type(4)));

#define BSH  8           // bucket = 256 nodes
#define NBKMAX 256       // >= ceil(50000/256)=196
#define EPB  4096        // edges per block in hist/bin passes
#define MBLK 392         // persistent MFMA-MLP grid (1568 waves)

__device__ __forceinline__ void addu(float* a, uint d) {
    __half2 h = *(__half2*)&d;
    a[0] += __low2float(h);
    a[1] += __high2float(h);
}
__device__ __forceinline__ half8 as_half8(uint4 u) {
    union { uint4 u; half8 h; } x; x.u = u; return x.h;
}

// ---------------- pack x,pos -> f16 rows [N x 32B] ----------------

__global__ __launch_bounds__(256) void pack_x(
    const float* __restrict__ x, const float* __restrict__ pos,
    uint2* __restrict__ xp2, int N)
{
    int i = blockIdx.x * 256 + threadIdx.x;
    if (i >= N) return;
    float v[16];
#pragma unroll
    for (int k = 0; k < 11; k++) v[k] = x[(size_t)i * 11 + k];
    v[11] = pos[(size_t)i * 3 + 0];
    v[12] = pos[(size_t)i * 3 + 1];
    v[13] = pos[(size_t)i * 3 + 2];
    v[14] = 0.f; v[15] = 0.f;
#pragma unroll
    for (int c = 0; c < 4; c++) {
        __half2 l = __floats2half2_rn(v[4 * c],     v[4 * c + 1]);
        __half2 h = __floats2half2_rn(v[4 * c + 2], v[4 * c + 3]);
        uint2 u;
        u.x = *(uint*)&l;
        u.y = *(uint*)&h;
        xp2[(size_t)i * 4 + c] = u;
    }
}

// ---------------- bucket histogram (LDS-privatized) ----------------

__global__ __launch_bounds__(256) void bucket_hist(
    const int* __restrict__ dst, int* __restrict__ bkt_cnt, int nbk, int E)
{
    __shared__ int lb[NBKMAX];
    for (int i = threadIdx.x; i < nbk; i += 256) lb[i] = 0;
    __syncthreads();
    int e0 = blockIdx.x * EPB + threadIdx.x;
#pragma unroll
    for (int j = 0; j < EPB / 256; j++) {
        int e = e0 + j * 256;
        if (e < E) atomicAdd(&lb[dst[e] >> BSH], 1);
    }
    __syncthreads();
    for (int i = threadIdx.x; i < nbk; i += 256) {
        int c = lb[i];
        if (c) atomicAdd(&bkt_cnt[i], c);
    }
}

// ---------------- bucket-offset scan (single block) ----------------

__global__ __launch_bounds__(256) void scan_small(
    const int* __restrict__ cnt, int* __restrict__ off,
    int* __restrict__ cur, int nbk)
{
    __shared__ int wsum[4];
    int i = threadIdx.x;
    int v = (i < nbk) ? cnt[i] : 0;
    int lane = threadIdx.x & 63, w = threadIdx.x >> 6;
    int s = v;
#pragma unroll
    for (int off2 = 1; off2 < 64; off2 <<= 1) {
        int t = __shfl_up(s, off2, 64);
        if (lane >= off2) s += t;
    }
    if (lane == 63) wsum[w] = s;
    __syncthreads();
    int add = 0;
    for (int j = 0; j < w; j++) add += wsum[j];
    int incl = s + add;
    if (i < nbk) { off[i] = incl - v; cur[i] = incl - v; }
    if (i == nbk - 1) off[nbk] = incl;   // == E
}

// ---------------- pass 1: bin edges into bucket-contiguous runs ----------------

__global__ __launch_bounds__(256) void bin_pairs(
    const int* __restrict__ src, const int* __restrict__ dst,
    int* __restrict__ bkt_cur, uint* __restrict__ pairs, int nbk, int E)
{
    __shared__ int lcnt[NBKMAX];
    __shared__ int lbase[NBKMAX];
    for (int i = threadIdx.x; i < nbk; i += 256) lcnt[i] = 0;
    __syncthreads();
    int e0 = blockIdx.x * EPB + threadIdx.x;
    uint pv[EPB / 256];
    int  rk[EPB / 256], bk[EPB / 256];
#pragma unroll
    for (int j = 0; j < EPB / 256; j++) {
        int e = e0 + j * 256;
        bk[j] = -1;
        if (e < E) {
            int s = src[e];
            int d = dst[e];
            bk[j] = d >> BSH;
            pv[j] = ((uint)(d & ((1 << BSH) - 1)) << 16) | (uint)s;  // N<65536
            rk[j] = atomicAdd(&lcnt[bk[j]], 1);
        }
    }
    __syncthreads();
    for (int i = threadIdx.x; i < nbk; i += 256) {
        int c = lcnt[i];
        lbase[i] = c ? atomicAdd(&bkt_cur[i], c) : 0;
    }
    __syncthreads();
#pragma unroll
    for (int j = 0; j < EPB / 256; j++) {
        if (bk[j] >= 0)
            pairs[(size_t)lbase[bk[j]] + rk[j]] = pv[j];
    }
}

// ---------------- pass 2: per-bucket deg/offs/ssrc (all LDS-local) ----------

__global__ __launch_bounds__(256) void bucket_build(
    const uint* __restrict__ pairs, const int* __restrict__ bkt_off,
    int* __restrict__ offs, int* __restrict__ deg,
    int* __restrict__ ssrc, int N)
{
    __shared__ int cnt[1 << BSH];
    __shared__ int cur[1 << BSH];
    __shared__ int wsum[4];
    int b = blockIdx.x;
    int nbase = b << BSH;
    int nn = min(1 << BSH, N - nbase);
    cnt[threadIdx.x] = 0;
    __syncthreads();
    int start = bkt_off[b], end = bkt_off[b + 1];
    for (int e = start + threadIdx.x; e < end; e += 256)
        atomicAdd(&cnt[pairs[e] >> 16], 1);
    __syncthreads();
    int v = cnt[threadIdx.x];
    int lane = threadIdx.x & 63, w = threadIdx.x >> 6;
    int s = v;
#pragma unroll
    for (int off2 = 1; off2 < 64; off2 <<= 1) {
        int t = __shfl_up(s, off2, 64);
        if (lane >= off2) s += t;
    }
    if (lane == 63) wsum[w] = s;
    __syncthreads();
    int add = 0;
    for (int j = 0; j < w; j++) add += wsum[j];
    int gofs = start + (s + add - v);
    if (threadIdx.x < nn) {
        offs[nbase + threadIdx.x] = gofs;
        deg[nbase + threadIdx.x]  = v;
    }
    cur[threadIdx.x] = gofs;
    __syncthreads();
    for (int e = start + threadIdx.x; e < end; e += 256) {
        uint pr = pairs[e];
        int p = atomicAdd(&cur[pr >> 16], 1);
        ssrc[p] = (int)(pr & 0xffffu);
    }
}

// ---------------- gather1: z0 = self + sum_nbr xp -> f16 rows [N x 32B] ----

__global__ __launch_bounds__(256) void gather1(
    const uint2* __restrict__ xp2,
    const int* __restrict__ offs, const int* __restrict__ deg,
    const int* __restrict__ ssrc,
    uint2* __restrict__ z0h2, int N)
{
    int lane = threadIdx.x & 63;
    int i = blockIdx.x * 4 + (threadIdx.x >> 6);
    if (i >= N) return;
    int j = lane >> 2;           // row slot 0..15
    int c = lane & 3;            // dword-pair: features 4c..4c+3
    int st = offs[i], len = deg[i];
    float a[4] = {0.f, 0.f, 0.f, 0.f};
    int k = 0;
    while (k < len) {
        int chunk = min(len - k, 64);
        int sv = ssrc[st + k + min(lane, chunk - 1)];
        int t = 0;
        for (; t + 32 <= chunk; t += 32) {
            int sA = __shfl(sv, t + j, 64);
            int sB = __shfl(sv, t + 16 + j, 64);
            uint2 A = xp2[(size_t)sA * 4 + c];
            uint2 B = xp2[(size_t)sB * 4 + c];
            addu(a + 0, A.x); addu(a + 2, A.y);
            addu(a + 0, B.x); addu(a + 2, B.y);
        }
        for (; t + 16 <= chunk; t += 16) {
            int sA = __shfl(sv, t + j, 64);
            uint2 A = xp2[(size_t)sA * 4 + c];
            addu(a + 0, A.x); addu(a + 2, A.y);
        }
        if (t < chunk) {
            int r = chunk - t;
            int sA = __shfl(sv, t + min(j, r - 1), 64);
            uint2 A = xp2[(size_t)sA * 4 + c];
            if (j < r) { addu(a + 0, A.x); addu(a + 2, A.y); }
        }
        k += chunk;
    }
#pragma unroll
    for (int m = 4; m < 64; m <<= 1)
#pragma unroll
        for (int d = 0; d < 4; d++) a[d] += __shfl_xor(a[d], m, 64);
    uint2 S = xp2[(size_t)i * 4 + c];            // self
    addu(a + 0, S.x); addu(a + 2, S.y);
    if (lane < 4) {                              // c == lane
        __half2 l = __floats2half2_rn(a[0], a[1]);
        __half2 h = __floats2half2_rn(a[2], a[3]);
        uint2 u;
        u.x = *(uint*)&l;
        u.y = *(uint*)&h;
        z0h2[(size_t)i * 4 + lane] = u;
    }
}

// ---------------- mlp1 (MFMA): h1 = relu(MLP(z0)) -> f16 rows ----------

__global__ __launch_bounds__(256) void mlp1_mfma(
    const uint4* __restrict__ z0h4,
    const float* __restrict__ W1a, const float* __restrict__ b1a,
    const float* __restrict__ W1b, const float* __restrict__ b1b,
    uint* __restrict__ h1p, int N, int nwaves)
{
    __shared__ float hb[4][16 * 68];
    int lane = threadIdx.x & 63;
    int wid  = threadIdx.x >> 6;
    float* h = hb[wid];
    int wv = blockIdx.x * 4 + wid;
    int m = lane & 15, quad = lane >> 4;
    int half = lane >> 5, p = lane & 31;

    // B-fragments in VGPRs (built once). B[k][n]: n=lane&15, k=quad*8+j.
    half8 BA[4];        // layer A, K=32 (k>=14 zero)
    half8 BB[4][2];     // layer B, K=64
    float ba[4], bb[4];
#pragma unroll
    for (int t = 0; t < 4; t++) {
#pragma unroll
        for (int j = 0; j < 8; j++) {
            int k = quad * 8 + j;
            BA[t][j] = (k < 14) ? (_Float16)W1a[k * 64 + t * 16 + m]
                                : (_Float16)0.f;
        }
#pragma unroll
        for (int hh = 0; hh < 2; hh++)
#pragma unroll
            for (int j = 0; j < 8; j++) {
                int k = hh * 32 + quad * 8 + j;
                BB[t][hh][j] = (_Float16)W1b[k * 64 + t * 16 + m];
            }
        ba[t] = b1a[t * 16 + m];
        bb[t] = b1b[t * 16 + m];
    }

    const int NG = N >> 4;                 // 16-node groups (N%16==0)
    int gpw = (NG + nwaves - 1) / nwaves;
    int g0 = wv * gpw, g1 = min(g0 + gpw, NG);

    for (int g = g0; g < g1; g++) {
        int i0 = g << 4;
        // A-frag: A[m][k=quad*8+j]; z0 rows are 32B (16 f16), quads 2,3 zero
        half8 A0;
#pragma unroll
        for (int j = 0; j < 8; j++) A0[j] = (_Float16)0.f;
        if (quad < 2)
            A0 = as_half8(z0h4[(size_t)(i0 + m) * 2 + quad]);
        f32x4 acc[4];
#pragma unroll
        for (int t = 0; t < 4; t++) {
            acc[t] = (f32x4){ba[t], ba[t], ba[t], ba[t]};
            acc[t] = __builtin_amdgcn_mfma_f32_16x16x32_f16(A0, BA[t], acc[t], 0, 0, 0);
        }
        // relu, C-layout (row=quad*4+r, col=t*16+m) -> LDS h[row][col]
#pragma unroll
        for (int t = 0; t < 4; t++)
#pragma unroll
            for (int r = 0; r < 4; r++)
                h[(quad * 4 + r) * 68 + t * 16 + m] = fmaxf(acc[t][r], 0.f);
        // layer B A-frags from LDS (wave-private, DS ops in-order)
        half8 A1[2];
#pragma unroll
        for (int hh = 0; hh < 2; hh++)
#pragma unroll
            for (int j = 0; j < 8; j++)
                A1[hh][j] = (_Float16)h[m * 68 + hh * 32 + quad * 8 + j];
        f32x4 acc2[4];
#pragma unroll
        for (int t = 0; t < 4; t++) {
            acc2[t] = (f32x4){bb[t], bb[t], bb[t], bb[t]};
            acc2[t] = __builtin_amdgcn_mfma_f32_16x16x32_f16(A1[0], BB[t][0], acc2[t], 0, 0, 0);
            acc2[t] = __builtin_amdgcn_mfma_f32_16x16x32_f16(A1[1], BB[t][1], acc2[t], 0, 0, 0);
        }
#pragma unroll
        for (int t = 0; t < 4; t++)
#pragma unroll
            for (int r = 0; r < 4; r++)
                h[(quad * 4 + r) * 68 + t * 16 + m] = fmaxf(acc2[t][r], 0.f);
        // coalesced f16 store: 2 rows (256B) per iteration
#pragma unroll
        for (int nn = 0; nn < 16; nn += 2) {
            int row = nn + half;
            float lo = h[row * 68 + 2 * p];
            float hi = h[row * 68 + 2 * p + 1];
            __half2 hh2 = __floats2half2_rn(lo, hi);
            h1p[(size_t)(i0 + row) * 32 + p] = *(uint*)&hh2;
        }
    }
}

// ---------------- gather2: z1 = self + sum_nbr h1, 8 rows/load ----------------

__global__ __launch_bounds__(256) void gather2(
    const uint4* __restrict__ h4,
    const int* __restrict__ offs, const int* __restrict__ deg,
    const int* __restrict__ ssrc,
    uint4* __restrict__ z4, int N)
{
    int lane = threadIdx.x & 63;
    int i = blockIdx.x * 4 + (threadIdx.x >> 6);
    if (i >= N) return;
    int j = lane >> 3;           // row slot 0..7
    int q = lane & 7;            // uint4 index: features 8q..8q+7
    int st = offs[i], len = deg[i];
    float a[8] = {0.f, 0.f, 0.f, 0.f, 0.f, 0.f, 0.f, 0.f};
    int k = 0;
    while (k < len) {
        int chunk = min(len - k, 64);
        int sv = ssrc[st + k + min(lane, chunk - 1)];
        int t = 0;
        for (; t + 32 <= chunk; t += 32) {
            int sA = __shfl(sv, t + j, 64);
            int sB = __shfl(sv, t + 8 + j, 64);
            int sC = __shfl(sv, t + 16 + j, 64);
            int sD = __shfl(sv, t + 24 + j, 64);
            uint4 A = h4[(size_t)sA * 8 + q];
            uint4 B = h4[(size_t)sB * 8 + q];
            uint4 C = h4[(size_t)sC * 8 + q];
            uint4 D = h4[(size_t)sD * 8 + q];
            addu(a + 0, A.x); addu(a + 2, A.y); addu(a + 4, A.z); addu(a + 6, A.w);
            addu(a + 0, B.x); addu(a + 2, B.y); addu(a + 4, B.z); addu(a + 6, B.w);
            addu(a + 0, C.x); addu(a + 2, C.y); addu(a + 4, C.z); addu(a + 6, C.w);
            addu(a + 0, D.x); addu(a + 2, D.y); addu(a + 4, D.z); addu(a + 6, D.w);
        }
        for (; t + 16 <= chunk; t += 16) {
            int sA = __shfl(sv, t + j, 64);
            int sB = __shfl(sv, t + 8 + j, 64);
            uint4 A = h4[(size_t)sA * 8 + q];
            uint4 B = h4[(size_t)sB * 8 + q];
            addu(a + 0, A.x); addu(a + 2, A.y); addu(a + 4, A.z); addu(a + 6, A.w);
            addu(a + 0, B.x); addu(a + 2, B.y); addu(a + 4, B.z); addu(a + 6, B.w);
        }
        for (; t + 8 <= chunk; t += 8) {
            int sA = __shfl(sv, t + j, 64);
            uint4 A = h4[(size_t)sA * 8 + q];
            addu(a + 0, A.x); addu(a + 2, A.y); addu(a + 4, A.z); addu(a + 6, A.w);
        }
        if (t < chunk) {
            int r = chunk - t;
            int sA = __shfl(sv, t + min(j, r - 1), 64);
            uint4 A = h4[(size_t)sA * 8 + q];
            if (j < r) {
                addu(a + 0, A.x); addu(a + 2, A.y);
                addu(a + 4, A.z); addu(a + 6, A.w);
            }
        }
        k += chunk;
    }
#pragma unroll
    for (int m = 8; m < 64; m <<= 1)
#pragma unroll
        for (int d = 0; d < 8; d++) a[d] += __shfl_xor(a[d], m, 64);
    uint4 S = h4[(size_t)i * 8 + q];             // self
    addu(a + 0, S.x); addu(a + 2, S.y); addu(a + 4, S.z); addu(a + 6, S.w);
    if (lane < 8) {
        __half2 p0 = __floats2half2_rn(a[0], a[1]);
        __half2 p1 = __floats2half2_rn(a[2], a[3]);
        __half2 p2 = __floats2half2_rn(a[4], a[5]);
        __half2 p3 = __floats2half2_rn(a[6], a[7]);
        uint4 o4;
        o4.x = *(uint*)&p0; o4.y = *(uint*)&p1;
        o4.z = *(uint*)&p2; o4.w = *(uint*)&p3;
        z4[(size_t)i * 8 + lane] = o4;
    }
}

// ---------------- mlp2 + pooling (MFMA) ----------------

__global__ __launch_bounds__(256) void mlp2pool_mfma(
    const uint4* __restrict__ z1p4,
    const float* __restrict__ W2a, const float* __restrict__ b2a,
    const float* __restrict__ W2b, const float* __restrict__ b2b,
    const int* __restrict__ batch,
    float* __restrict__ sums, float* __restrict__ counts, int N, int nwaves)
{
    __shared__ float hb[4][16 * 68];
    int lane = threadIdx.x & 63;
    int wid  = threadIdx.x >> 6;
    float* h = hb[wid];
    int wv = blockIdx.x * 4 + wid;
    int m = lane & 15, quad = lane >> 4;

    half8 BA[4][2], BB[4][2];
    float ba[4], bb[4];
#pragma unroll
    for (int t = 0; t < 4; t++) {
#pragma unroll
        for (int hh = 0; hh < 2; hh++)
#pragma unroll
            for (int j = 0; j < 8; j++) {
                int k = hh * 32 + quad * 8 + j;
                BA[t][hh][j] = (_Float16)W2a[k * 64 + t * 16 + m];
                BB[t][hh][j] = (_Float16)W2b[k * 64 + t * 16 + m];
            }
        ba[t] = b2a[t * 16 + m];
        bb[t] = b2b[t * 16 + m];
    }

    const int NG = N >> 4;
    int gpw = (NG + nwaves - 1) / nwaves;
    int g0 = wv * gpw, g1 = min(g0 + gpw, NG);

    int gcur = -1; float ps = 0.f; int cnt = 0;

    for (int g = g0; g < g1; g++) {
        int i0 = g << 4;
        // A-frags from z1p (rows 128B): uint4 idx = hh*4+quad
        half8 A0[2];
#pragma unroll
        for (int hh = 0; hh < 2; hh++)
            A0[hh] = as_half8(z1p4[(size_t)(i0 + m) * 8 + hh * 4 + quad]);
        f32x4 acc[4];
#pragma unroll
        for (int t = 0; t < 4; t++) {
            acc[t] = (f32x4){ba[t], ba[t], ba[t], ba[t]};
            acc[t] = __builtin_amdgcn_mfma_f32_16x16x32_f16(A0[0], BA[t][0], acc[t], 0, 0, 0);
            acc[t] = __builtin_amdgcn_mfma_f32_16x16x32_f16(A0[1], BA[t][1], acc[t], 0, 0, 0);
        }
#pragma unroll
        for (int t = 0; t < 4; t++)
#pragma unroll
            for (int r = 0; r < 4; r++)
                h[(quad * 4 + r) * 68 + t * 16 + m] = fmaxf(acc[t][r], 0.f);
        half8 A1[2];
#pragma unroll
        for (int hh = 0; hh < 2; hh++)
#pragma unroll
            for (int j = 0; j < 8; j++)
                A1[hh][j] = (_Float16)h[m * 68 + hh * 32 + quad * 8 + j];
        f32x4 acc2[4];
#pragma unroll
        for (int t = 0; t < 4; t++) {
            acc2[t] = (f32x4){bb[t], bb[t], bb[t], bb[t]};
            acc2[t] = __builtin_amdgcn_mfma_f32_16x16x32_f16(A1[0], BB[t][0], acc2[t], 0, 0, 0);
            acc2[t] = __builtin_amdgcn_mfma_f32_16x16x32_f16(A1[1], BB[t][1], acc2[t], 0, 0, 0);
        }
#pragma unroll
        for (int t = 0; t < 4; t++)
#pragma unroll
            for (int r = 0; r < 4; r++)
                h[(quad * 4 + r) * 68 + t * 16 + m] = fmaxf(acc2[t][r], 0.f);
        // pooling: lane = feature 0..63; batch sorted; contiguous node range
#pragma unroll
        for (int nn = 0; nn < 16; nn++) {
            float v = h[nn * 68 + lane];           // already relu'ed
            int gi = batch[i0 + nn];
            if (gi != gcur) {
                if (gcur >= 0) {
                    atomicAdd(&sums[gcur * 64 + lane], ps);
                    if (lane == 0) atomicAdd(&counts[gcur], (float)cnt);
                }
                gcur = gi; ps = 0.f; cnt = 0;
            }
            ps += v; cnt++;
        }
    }
    if (gcur >= 0) {
        atomicAdd(&sums[gcur * 64 + lane], ps);
        if (lane == 0) atomicAdd(&counts[gcur], (float)cnt);
    }
}

__global__ __launch_bounds__(256) void gin_final(
    const float* __restrict__ sums, const float* __restrict__ counts,
    const float* __restrict__ Wlin, const float* __restrict__ blin,
    float* __restrict__ out, int G)
{
    int lane = threadIdx.x & 63;
    int g    = blockIdx.x * 4 + (threadIdx.x >> 6);
    if (g < G) {
        float v = sums[g * 64 + lane] * Wlin[lane];
#pragma unroll
        for (int off = 32; off > 0; off >>= 1) v += __shfl_down(v, off, 64);
        if (lane == 0) out[g] = v / fmaxf(counts[g], 1.0f) + blin[0];
    }
}

extern "C" void kernel_launch(void* const* d_in, const int* in_sizes, int n_in,
                              void* d_out, int out_size, void* d_ws, size_t ws_size,
                              hipStream_t stream) {
    const float* x    = (const float*)d_in[0];
    const float* pos  = (const float*)d_in[1];
    const int*   ei   = (const int*)d_in[2];
    const int*   batch= (const int*)d_in[3];
    const float* W1a  = (const float*)d_in[4];
    const float* b1a  = (const float*)d_in[5];
    const float* W1b  = (const float*)d_in[6];
    const float* b1b  = (const float*)d_in[7];
    const float* W2a  = (const float*)d_in[8];
    const float* b2a  = (const float*)d_in[9];
    const float* W2b  = (const float*)d_in[10];
    const float* b2b  = (const float*)d_in[11];
    const float* Wlin = (const float*)d_in[12];
    const float* blin = (const float*)d_in[13];
    float* out = (float*)d_out;

    const int N = in_sizes[0] / 11;     // 50000 (<65536 for u32 pairs; %16==0)
    const int E = in_sizes[2] / 2;      // 800000
    const int G = out_size;             // 2500

    const int* src = ei;
    const int* dst = ei + E;
    const int nbk = (N + (1 << BSH) - 1) >> BSH;   // 196
    const int neb = (E + EPB - 1) / EPB;           // 196

    // Workspace:
    // [sums|counts|bkt_cnt](memset) |offs|deg|bkt_off|bkt_cur|ssrc|h1p|xp|
    // zunion { pairs (E u32) / z0h (N*32B f16) / z1p (N*128B f16) }
    char* ws = (char*)d_ws;
    size_t o = 0;
    float* sums    = (float*)(ws + o); o += (size_t)G * 64 * 4;
    float* counts  = (float*)(ws + o); o += (((size_t)G + 63) & ~(size_t)63) * 4;
    int*   bkt_cnt = (int*)(ws + o);   o += NBKMAX * 4;
    size_t zero_bytes = o;
    int*   offs    = (int*)(ws + o);   o += (size_t)N * 4;
    int*   deg     = (int*)(ws + o);   o += (size_t)N * 4;
    int*   bkt_off = (int*)(ws + o);   o += (NBKMAX + 1) * 4;
    int*   bkt_cur = (int*)(ws + o);   o += NBKMAX * 4;
    int*   ssrc    = (int*)(ws + o);   o += (size_t)E * 4;
    o = (o + 255) & ~(size_t)255;
    uint*  h1p     = (uint*)(ws + o);  o += (size_t)N * 32 * 4;
    o = (o + 255) & ~(size_t)255;
    uint2* xp2     = (uint2*)(ws + o); o += (size_t)N * 32;
    o = (o + 255) & ~(size_t)255;
    uint*  pairs   = (uint*)(ws + o);  // E u32 (3.2 MB)   } dead before gather1
    uint*  z0h     = (uint*)(ws + o);  // N*32B (1.6 MB)   } dead after mlp1
    uint*  z1p     = (uint*)(ws + o);  // N*128B (6.4 MB)  } written by gather2

    hipMemsetAsync(ws, 0, zero_bytes, stream);

    pack_x<<<(N + 255) / 256, 256, 0, stream>>>(x, pos, xp2, N);
    bucket_hist<<<neb, 256, 0, stream>>>(dst, bkt_cnt, nbk, E);
    scan_small<<<1, 256, 0, stream>>>(bkt_cnt, bkt_off, bkt_cur, nbk);
    bin_pairs<<<neb, 256, 0, stream>>>(src, dst, bkt_cur, pairs, nbk, E);
    bucket_build<<<nbk, 256, 0, stream>>>(pairs, bkt_off, offs, deg, ssrc, N);

    gather1<<<(N + 3) / 4, 256, 0, stream>>>(
        xp2, offs, deg, ssrc, (uint2*)z0h, N);
    mlp1_mfma<<<MBLK, 256, 0, stream>>>(
        (const uint4*)z0h, W1a, b1a, W1b, b1b, h1p, N, MBLK * 4);
    gather2<<<(N + 3) / 4, 256, 0, stream>>>(
        (const uint4*)h1p, offs, deg, ssrc, (uint4*)z1p, N);
    mlp2pool_mfma<<<MBLK, 256, 0, stream>>>(
        (const uint4*)z1p, W2a, b2a, W2b, b2b, batch, sums, counts, N, MBLK * 4);

    gin_final<<<(G + 3) / 4, 256, 0, stream>>>(
        sums, counts, Wlin, blin, out, G);
}